// Round 6
// baseline (142.554 us; speedup 1.0000x reference)
//
#include <hip/hip_runtime.h>

#define NPIX (512*512)
#define KCL 16
#define IMG_STRIDE 544     // per-image floats: [16]=wsum, [32..543]=sums[16][32]
#define HP_OFF 4352        // histpart[8][16][16] floats (atomic, memset-zeroed)
#define LAB_OFF 8192       // packed u8 labels, NPIX*8 bytes = 2 MB
#define ZERO_BYTES ((HP_OFF + 8*16*16) * sizeof(float))

// reduce-scatter one level: keep lo/hi half by lane bit, exchange the other.
#define RS_LEVEL(ARR, HALF, MASK) { \
    const bool hi = (lane & (MASK)) != 0; \
    _Pragma("unroll") \
    for (int j = 0; j < (HALF); ++j) { \
      float send = hi ? ARR[j] : ARR[j + (HALF)]; \
      float recv = __shfl_xor(send, (MASK), 64); \
      ARR[j] = (hi ? ARR[j + (HALF)] : ARR[j]) + recv; \
    } }

// ---------------- prep: pack labels to u8 + per-(img,seg) histogram ----------------
// 128 blocks = 8 img x 16 seg; 512 threads; 32 labels/thread.
__global__ void __launch_bounds__(512)
cl_prep(const int* __restrict__ labs, float* __restrict__ ws)
{
  const int b    = blockIdx.x >> 4;
  const int seg  = blockIdx.x & 15;
  const int tid  = threadIdx.x;
  const int lane = tid & 63;
  const int4* lb4 = reinterpret_cast<const int4*>(labs + b * NPIX + seg * 16384);
  unsigned int* lab8 = reinterpret_cast<unsigned int*>(ws + LAB_OFF) +
                       (b * NPIX + seg * 16384) / 4;

  float c[KCL];
  #pragma unroll
  for (int k = 0; k < KCL; ++k) c[k] = 0.f;
  #pragma unroll
  for (int i = 0; i < 8; ++i) {
    const int4 v = lb4[tid + i * 512];
    lab8[tid + i * 512] = (unsigned int)(v.x & 15) | ((unsigned int)(v.y & 15) << 8) |
                          ((unsigned int)(v.z & 15) << 16) | ((unsigned int)(v.w & 15) << 24);
    #pragma unroll
    for (int k = 0; k < KCL; ++k) {
      c[k] += (v.x == k) ? 1.0f : 0.0f;
      c[k] += (v.y == k) ? 1.0f : 0.0f;
      c[k] += (v.z == k) ? 1.0f : 0.0f;
      c[k] += (v.w == k) ? 1.0f : 0.0f;
    }
  }
  RS_LEVEL(c, 8, 1)
  RS_LEVEL(c, 4, 2)
  RS_LEVEL(c, 2, 4)
  RS_LEVEL(c, 1, 8)
  c[0] += __shfl_xor(c[0], 16, 64);
  c[0] += __shfl_xor(c[0], 32, 64);
  if (lane < KCL) {
    const int v4 = (int)(__brev((unsigned)lane) >> 28);
    atomicAdd(&ws[HP_OFF + (b * 16 + seg) * KCL + v4], c[0]);
  }
}

// ---------------- accum: LDS-staged linear-stream kernel ----------------
// grid 512 = 8 img x 4 chgroups x 16 pxtiles; 512 threads = 8 waves.
// Wave w streams ONE channel (cg*8+w) linearly, 4 KB/round, 16 rounds.
// Compute: wave w does 4 staged channels ((w>>2)*4..+3) x px-quarter (w&3),
// identical inner body to round 3. Double-buffered LDS.
__global__ void __launch_bounds__(512, 4)
cl_accum(const float* __restrict__ feats, float* __restrict__ ws)
{
  const int bid  = blockIdx.x;
  const int pt   = bid & 15;
  const int cg   = (bid >> 4) & 3;
  const int b    = bid >> 6;
  const int tid  = threadIdx.x;
  const int wave = tid >> 6;
  const int lane = tid & 63;

  __shared__ float sfeat[2][8][1024];
  __shared__ float swei[2][1024];
  __shared__ unsigned int slab[2][256];
  __shared__ float scnt[KCL];
  __shared__ float sinvt[KCL];

  // per-image cnt from prep partials -> invt LUT
  if (tid < KCL) scnt[tid] = 0.f;
  __syncthreads();
  if (tid < 256)
    atomicAdd(&scnt[tid & 15], ws[HP_OFF + (b * 16 + (tid >> 4)) * KCL + (tid & 15)]);
  __syncthreads();
  if (tid < KCL) sinvt[tid] = 1.0f / scnt[tid];
  __syncthreads();

  const float* fptr = feats + ((long long)(b * 32 + cg * 8 + wave)) * NPIX + pt * 16384;
  const unsigned int* lptr = reinterpret_cast<const unsigned int*>(ws + LAB_OFF) +
                             (b * NPIX + pt * 16384) / 4;

  float acc[4][KCL];
  #pragma unroll
  for (int ch = 0; ch < 4; ++ch)
    #pragma unroll
    for (int k = 0; k < KCL; ++k) acc[ch][k] = 0.f;
  float wsum = 0.f;

  float4 pf[4];
  unsigned int plw = 0;

  // prologue: stage round 0
  #pragma unroll
  for (int i = 0; i < 4; ++i)
    pf[i] = *reinterpret_cast<const float4*>(fptr + i * 256 + lane * 4);
  if (tid < 256) plw = lptr[tid];
  #pragma unroll
  for (int i = 0; i < 4; ++i)
    *reinterpret_cast<float4*>(&sfeat[0][wave][i * 256 + lane * 4]) = pf[i];
  if (tid < 256) {
    slab[0][tid] = plw;
    float4 f;
    f.x = sinvt[plw & 15];
    f.y = sinvt[(plw >> 8) & 15];
    f.z = sinvt[(plw >> 16) & 15];
    f.w = sinvt[(plw >> 24) & 15];
    *reinterpret_cast<float4*>(&swei[0][tid * 4]) = f;
  }
  __syncthreads();

  const int chg = wave >> 2;       // staged channel rows chg*4..chg*4+3
  const int pxq = wave & 3;        // px quarter
  const int p   = pxq * 256 + lane * 4;

  for (int r = 0; r < 16; ++r) {
    const int cur = r & 1, nxt = cur ^ 1;
    if (r < 15) {                  // issue next round's global loads early
      #pragma unroll
      for (int i = 0; i < 4; ++i)
        pf[i] = *reinterpret_cast<const float4*>(fptr + (r + 1) * 1024 + i * 256 + lane * 4);
      if (tid < 256) plw = lptr[(r + 1) * 256 + tid];
    }

    // ---- compute round r from buf[cur] (R3 inner body) ----
    {
      const unsigned int labw = slab[cur][pxq * 64 + lane];
      const float4 w4 = *reinterpret_cast<const float4*>(&swei[cur][p]);
      const float4 a0 = *reinterpret_cast<const float4*>(&sfeat[cur][chg * 4 + 0][p]);
      const float4 a1 = *reinterpret_cast<const float4*>(&sfeat[cur][chg * 4 + 1][p]);
      const float4 a2 = *reinterpret_cast<const float4*>(&sfeat[cur][chg * 4 + 2][p]);
      const float4 a3 = *reinterpret_cast<const float4*>(&sfeat[cur][chg * 4 + 3][p]);
      const float va0[4] = {a0.x, a0.y, a0.z, a0.w};
      const float va1[4] = {a1.x, a1.y, a1.z, a1.w};
      const float va2[4] = {a2.x, a2.y, a2.z, a2.w};
      const float va3[4] = {a3.x, a3.y, a3.z, a3.w};
      const float vw[4]  = {w4.x, w4.y, w4.z, w4.w};
      #pragma unroll
      for (int px = 0; px < 4; ++px) {
        const int lab = (int)((labw >> (8 * px)) & 0xFF);
        const float v0 = va0[px], v1 = va1[px], v2 = va2[px], v3 = va3[px];
        float sq = v0 * v0;
        sq = fmaf(v1, v1, sq);
        sq = fmaf(v2, v2, sq);
        sq = fmaf(v3, v3, sq);
        wsum = fmaf(vw[px], sq, wsum);
        #pragma unroll
        for (int k = 0; k < KCL; ++k) {
          const float m = (lab == k) ? 1.0f : 0.0f;
          acc[0][k] = fmaf(m, v0, acc[0][k]);
          acc[1][k] = fmaf(m, v1, acc[1][k]);
          acc[2][k] = fmaf(m, v2, acc[2][k]);
          acc[3][k] = fmaf(m, v3, acc[3][k]);
        }
      }
    }
    __syncthreads();               // all waves done reading buf[cur]

    if (r < 15) {                  // write staged data into buf[nxt]
      #pragma unroll
      for (int i = 0; i < 4; ++i)
        *reinterpret_cast<float4*>(&sfeat[nxt][wave][i * 256 + lane * 4]) = pf[i];
      if (tid < 256) {
        slab[nxt][tid] = plw;
        float4 f;
        f.x = sinvt[plw & 15];
        f.y = sinvt[(plw >> 8) & 15];
        f.z = sinvt[(plw >> 16) & 15];
        f.w = sinvt[(plw >> 24) & 15];
        *reinterpret_cast<float4*>(&swei[nxt][tid * 4]) = f;
      }
    }
    __syncthreads();               // buf[nxt] ready for round r+1
  }

  // ---- sums: 64 values -> reduce-scatter, lane l ends with value brev6(l) ----
  float a[64];
  #pragma unroll
  for (int ch = 0; ch < 4; ++ch)
    #pragma unroll
    for (int k = 0; k < KCL; ++k) a[ch * 16 + k] = acc[ch][k];

  RS_LEVEL(a, 32,  1)
  RS_LEVEL(a, 16,  2)
  RS_LEVEL(a,  8,  4)
  RS_LEVEL(a,  4,  8)
  RS_LEVEL(a,  2, 16)
  RS_LEVEL(a,  1, 32)

  {
    const int v6  = (int)(__brev((unsigned)lane) >> 26);   // original value index
    const int chl = v6 >> 4, k = v6 & 15;
    const int c   = cg * 8 + chg * 4 + chl;                // global channel
    atomicAdd(&ws[b * IMG_STRIDE + 32 + k * 32 + c], a[0]);
  }

  #pragma unroll
  for (int mk = 1; mk < 64; mk <<= 1) wsum += __shfl_xor(wsum, mk, 64);
  if (lane == 0) atomicAdd(&ws[b * IMG_STRIDE + 16], wsum);
}

// ---------------- finalize: 1 block, 512 threads; wave w = image w ----------------
__global__ void __launch_bounds__(512)
cl_finalize(const float* __restrict__ ws, float* __restrict__ out)
{
  __shared__ float smean[8][KCL][33];
  __shared__ float slossb[8];
  const int tid  = threadIdx.x;
  const int w    = tid >> 6;
  const int lane = tid & 63;
  const float* base = ws + w * IMG_STRIDE;

  // cnt[k] from prep partials (lane k<16 holds cnt_k)
  float cl = 0.f;
  if (lane < KCL) {
    #pragma unroll
    for (int s = 0; s < 16; ++s)
      cl += ws[HP_OFF + (w * 16 + s) * KCL + lane];
  }
  // lane's 8 (k,c) entries share k = lane>>2
  const float ck = __shfl(cl, lane >> 2, 64);
  const float ik = 1.0f / ck;

  float m2part = 0.f;
  #pragma unroll
  for (int j = 0; j < 8; ++j) {
    const int idx = lane * 8 + j;
    const int k = idx >> 5, c = idx & 31;
    const float m = base[32 + k * 32 + c] * ik;
    smean[w][k][c] = m;
    m2part = fmaf(m, m, m2part);
  }
  float varp = -m2part;
  if (lane == 0) varp += base[16];      // wsum = sum_k Sq_k / cnt_k
  #pragma unroll
  for (int mk = 1; mk < 64; mk <<= 1) varp += __shfl_xor(varp, mk, 64);

  __syncthreads();

  // reg term: 4 lanes per cluster k
  const int kk = lane >> 2, q = lane & 3;
  float n2 = 0.f;
  #pragma unroll
  for (int j = 0; j < 8; ++j) {
    const float m = smean[w][kk][q * 8 + j];
    n2 = fmaf(m, m, n2);
  }
  n2 += __shfl_xor(n2, 1, 64);
  n2 += __shfl_xor(n2, 2, 64);
  float regp = (q == 0) ? sqrtf(n2) : 0.f;
  #pragma unroll
  for (int mk = 1; mk < 64; mk <<= 1) regp += __shfl_xor(regp, mk, 64);

  // pairwise hinge over 120 pairs
  float hing = 0.f;
  for (int pp = lane; pp < 120; pp += 64) {
    int i = 0, rem = pp;
    while (rem >= 15 - i) { rem -= 15 - i; ++i; }
    const int jj = i + 1 + rem;
    float d2 = 0.f;
    #pragma unroll
    for (int c = 0; c < 32; ++c) {
      const float d = smean[w][i][c] - smean[w][jj][c];
      d2 = fmaf(d, d, d2);
    }
    const float h = fmaxf(5.0f - sqrtf(d2), 0.f);   // 2*DD = 5.0
    hing = fmaf(h, h, hing);
  }
  #pragma unroll
  for (int mk = 1; mk < 64; mk <<= 1) hing += __shfl_xor(hing, mk, 64);

  if (lane == 0)
    slossb[w] = (varp + hing * (1.0f / 15.0f) + 0.005f * regp) * (1.0f / 16.0f);
  __syncthreads();
  if (tid == 0) {
    float t = 0.f;
    #pragma unroll
    for (int i = 0; i < 8; ++i) t += slossb[i];
    out[0] = t * (1.0f / 9.0f);
  }
}

extern "C" void kernel_launch(void* const* d_in, const int* in_sizes, int n_in,
                              void* d_out, int out_size, void* d_ws, size_t ws_size,
                              hipStream_t stream)
{
  const float* feats = (const float*)d_in[0];
  const int*   labs  = (const int*)d_in[1];
  float* out = (float*)d_out;
  float* ws  = (float*)d_ws;

  hipMemsetAsync(d_ws, 0, ZERO_BYTES, stream);
  hipLaunchKernelGGL(cl_prep,     dim3(128), dim3(512), 0, stream, labs, ws);
  hipLaunchKernelGGL(cl_accum,    dim3(512), dim3(512), 0, stream, feats, ws);
  hipLaunchKernelGGL(cl_finalize, dim3(1),   dim3(512), 0, stream, ws, out);
}

// Round 8
// 68.749 us; speedup vs baseline: 2.0735x; 2.0735x over previous
//
#include <hip/hip_runtime.h>

#define NPIX (512*512)
#define KCL 16
#define IMG_STRIDE 1088   // per-image floats: [0..15]=cnt, [32..543]=sums[16][32], [544..1055]=sq[16][32]
#define ZERO_BYTES (8 * IMG_STRIDE * 4)

typedef __attribute__((ext_vector_type(8))) short bf16x8;
typedef __attribute__((ext_vector_type(4))) float f32x4;
typedef __attribute__((ext_vector_type(4))) int i32x4;

// fp32 -> bf16 with round-to-nearest-even (matches __float2bfloat16_rn for finite x)
static __device__ __forceinline__ unsigned int bf16rne(float x) {
  unsigned int u = __builtin_bit_cast(unsigned int, x);
  u += 0x7FFFu + ((u >> 16) & 1u);
  return u >> 16;
}
// pack two fp32 -> one dword of 2 bf16 (RNE), lo = a, hi = b
static __device__ __forceinline__ int pk2(float a, float b) {
  return (int)(bf16rne(a) | (bf16rne(b) << 16));
}

// reduce-scatter one level: keep lo/hi half by lane bit, exchange the other.
#define RS_LEVEL(ARR, HALF, MASK) { \
    const bool hi = (lane & (MASK)) != 0; \
    _Pragma("unroll") \
    for (int j = 0; j < (HALF); ++j) { \
      float send = hi ? ARR[j] : ARR[j + (HALF)]; \
      float recv = __shfl_xor(send, (MASK), 64); \
      ARR[j] = (hi ? ARR[j + (HALF)] : ARR[j]) + recv; \
    } }

// ---------------- accum: one-hot MFMA kernel ----------------
// 512 blocks = 8 img x 64 pxtiles(4096 px); 512 threads = 8 waves.
// Wave w owns px [w*512, w*512+512) of the tile as 16 groups of 32 px.
// Per group: A = onehot[k=lane&15][px], B = f[px][c] (bf16), two ch-halves,
// MFMA for sums and for squares. D col=lane&15 (k), row=(lane>>4)*4+r (c).
// A-fragment of lane l covers k=l&15 over px-slots; B-fragment covers
// c=l&15 over the same px-slots; since the result is summed over all px,
// any intra-lane K-ordering works as long as A and B agree (both use
// slot j = px (lane>>4)*8+j of the 32-px group).
__global__ void __launch_bounds__(512)
cl_accum(const float* __restrict__ feats, const int* __restrict__ labs,
         float* __restrict__ ws)
{
  const int bid  = blockIdx.x;
  const int tile = bid & 63;
  const int b    = bid >> 6;
  const int tid  = threadIdx.x;
  const int wave = tid >> 6;
  const int lane = tid & 63;
  const int px0  = tile * 4096;

  __shared__ unsigned int slabw[1024];   // packed u8 labels, 4096 px
  __shared__ float red[1024];            // [0..511]=sums[16][32], [512..1023]=sq
  __shared__ float hpart[8][KCL];

  // ---- stage labels (packed u8) + per-thread histogram of its 8 labels ----
  {
    float c[KCL];
    #pragma unroll
    for (int k = 0; k < KCL; ++k) c[k] = 0.f;
    const int4* lb4 = reinterpret_cast<const int4*>(labs + b * NPIX + px0);
    #pragma unroll
    for (int i = 0; i < 2; ++i) {
      const int4 v = lb4[tid + i * 512];
      slabw[tid + i * 512] = (unsigned int)v.x | ((unsigned int)v.y << 8) |
                             ((unsigned int)v.z << 16) | ((unsigned int)v.w << 24);
      #pragma unroll
      for (int k = 0; k < KCL; ++k) {
        c[k] += (v.x == k) ? 1.0f : 0.0f;
        c[k] += (v.y == k) ? 1.0f : 0.0f;
        c[k] += (v.z == k) ? 1.0f : 0.0f;
        c[k] += (v.w == k) ? 1.0f : 0.0f;
      }
    }
    // zero the reduce buffer
    red[tid] = 0.f;
    red[tid + 512] = 0.f;
    // wave-reduce hist: 16 values over 4 levels + fold across lane bits 4,5
    RS_LEVEL(c, 8, 1)
    RS_LEVEL(c, 4, 2)
    RS_LEVEL(c, 2, 4)
    RS_LEVEL(c, 1, 8)
    c[0] += __shfl_xor(c[0], 16, 64);
    c[0] += __shfl_xor(c[0], 32, 64);
    if (lane < KCL) {
      const int v4 = (int)(__brev((unsigned)lane) >> 28);
      hpart[wave][v4] = c[0];
    }
  }
  __syncthreads();
  if (tid < KCL) {
    float t = 0.f;
    #pragma unroll
    for (int w = 0; w < 8; ++w) t += hpart[w][tid];
    atomicAdd(&ws[b * IMG_STRIDE + tid], t);   // cnt
  }

  // ---- main MFMA loop ----
  const int kid = lane & 15;
  const int sub = lane >> 4;             // 0..3
  const float* fA = feats + ((long long)(b * 32 + kid)) * NPIX
                    + px0 + wave * 512 + sub * 8;
  const float* fB = fA + (long long)16 * NPIX;
  const unsigned long long* slq =
      reinterpret_cast<const unsigned long long*>(slabw) + wave * 64 + sub;

  f32x4 accs0 = {0.f, 0.f, 0.f, 0.f};
  f32x4 accs1 = {0.f, 0.f, 0.f, 0.f};
  f32x4 accq0 = {0.f, 0.f, 0.f, 0.f};
  f32x4 accq1 = {0.f, 0.f, 0.f, 0.f};

  #pragma unroll 4
  for (int g = 0; g < 16; ++g) {
    const unsigned long long lw = slq[g * 4];   // 8 labels for this lane's px
    bf16x8 af;
    #pragma unroll
    for (int j = 0; j < 8; ++j)
      af[j] = (short)((((int)(lw >> (8 * j)) & 0xFF) == kid) ? 0x3F80 : 0);

    // half 0: channels [0..15]
    {
      const float4 x0 = *reinterpret_cast<const float4*>(fA + g * 32);
      const float4 x1 = *reinterpret_cast<const float4*>(fA + g * 32 + 4);
      i32x4 wv, qv;
      wv[0] = pk2(x0.x, x0.y); wv[1] = pk2(x0.z, x0.w);
      wv[2] = pk2(x1.x, x1.y); wv[3] = pk2(x1.z, x1.w);
      qv[0] = pk2(x0.x * x0.x, x0.y * x0.y); qv[1] = pk2(x0.z * x0.z, x0.w * x0.w);
      qv[2] = pk2(x1.x * x1.x, x1.y * x1.y); qv[3] = pk2(x1.z * x1.z, x1.w * x1.w);
      accs0 = __builtin_amdgcn_mfma_f32_16x16x32_bf16(
                  af, __builtin_bit_cast(bf16x8, wv), accs0, 0, 0, 0);
      accq0 = __builtin_amdgcn_mfma_f32_16x16x32_bf16(
                  af, __builtin_bit_cast(bf16x8, qv), accq0, 0, 0, 0);
    }
    // half 1: channels [16..31]
    {
      const float4 x0 = *reinterpret_cast<const float4*>(fB + g * 32);
      const float4 x1 = *reinterpret_cast<const float4*>(fB + g * 32 + 4);
      i32x4 wv, qv;
      wv[0] = pk2(x0.x, x0.y); wv[1] = pk2(x0.z, x0.w);
      wv[2] = pk2(x1.x, x1.y); wv[3] = pk2(x1.z, x1.w);
      qv[0] = pk2(x0.x * x0.x, x0.y * x0.y); qv[1] = pk2(x0.z * x0.z, x0.w * x0.w);
      qv[2] = pk2(x1.x * x1.x, x1.y * x1.y); qv[3] = pk2(x1.z * x1.z, x1.w * x1.w);
      accs1 = __builtin_amdgcn_mfma_f32_16x16x32_bf16(
                  af, __builtin_bit_cast(bf16x8, wv), accs1, 0, 0, 0);
      accq1 = __builtin_amdgcn_mfma_f32_16x16x32_bf16(
                  af, __builtin_bit_cast(bf16x8, qv), accq1, 0, 0, 0);
    }
  }

  // ---- cross-wave LDS reduce, then per-block global atomics ----
  // C/D layout (m89-verified): col = lane&15 -> k? NO: A rows are k, so
  // D[row=k', col=c'] with col=lane&15 = channel-within-half via B cols,
  // row=(lane>>4)*4+r = cluster k. (A's M-dim = k, B's N-dim = c.)
  #pragma unroll
  for (int r = 0; r < 4; ++r) {
    const int k = sub * 4 + r;
    atomicAdd(&red[k * 32 + kid],            accs0[r]);
    atomicAdd(&red[k * 32 + 16 + kid],       accs1[r]);
    atomicAdd(&red[512 + k * 32 + kid],      accq0[r]);
    atomicAdd(&red[512 + k * 32 + 16 + kid], accq1[r]);
  }
  __syncthreads();
  atomicAdd(&ws[b * IMG_STRIDE + 32 + tid],  red[tid]);        // sums
  atomicAdd(&ws[b * IMG_STRIDE + 544 + tid], red[512 + tid]);  // sq
}

// ---------------- finalize: 1 block, 512 threads; wave w = image w ----------------
__global__ void __launch_bounds__(512)
cl_finalize(const float* __restrict__ ws, float* __restrict__ out)
{
  __shared__ float smean[8][KCL][33];
  __shared__ float slossb[8];
  const int tid  = threadIdx.x;
  const int w    = tid >> 6;
  const int lane = tid & 63;
  const float* base = ws + w * IMG_STRIDE;

  // lane covers 8 entries idx=lane*8+j, all with k = lane>>2
  const int kl = lane >> 2;
  const float ik = 1.0f / base[kl];

  float m2part = 0.f, sqpart = 0.f;
  #pragma unroll
  for (int j = 0; j < 8; ++j) {
    const int idx = lane * 8 + j;
    const int c = idx & 31;
    const float m = base[32 + idx] * ik;
    smean[w][kl][c] = m;
    m2part = fmaf(m, m, m2part);
    sqpart += base[544 + idx];
  }
  float varp = fmaf(sqpart, ik, -m2part);
  #pragma unroll
  for (int mk = 1; mk < 64; mk <<= 1) varp += __shfl_xor(varp, mk, 64);
  // varp == var_loss on all lanes

  __syncthreads();

  // reg term: 4 lanes per cluster k
  const int kk = lane >> 2, q = lane & 3;
  float n2 = 0.f;
  #pragma unroll
  for (int j = 0; j < 8; ++j) {
    const float m = smean[w][kk][q * 8 + j];
    n2 = fmaf(m, m, n2);
  }
  n2 += __shfl_xor(n2, 1, 64);
  n2 += __shfl_xor(n2, 2, 64);
  float regp = (q == 0) ? sqrtf(n2) : 0.f;
  #pragma unroll
  for (int mk = 1; mk < 64; mk <<= 1) regp += __shfl_xor(regp, mk, 64);

  // pairwise hinge over 120 pairs
  float hing = 0.f;
  for (int p = lane; p < 120; p += 64) {
    int i = 0, rem = p;
    while (rem >= 15 - i) { rem -= 15 - i; ++i; }
    const int jj = i + 1 + rem;
    float d2 = 0.f;
    #pragma unroll
    for (int c = 0; c < 32; ++c) {
      const float d = smean[w][i][c] - smean[w][jj][c];
      d2 = fmaf(d, d, d2);
    }
    const float h = fmaxf(5.0f - sqrtf(d2), 0.f);   // 2*DD = 5.0
    hing = fmaf(h, h, hing);
  }
  #pragma unroll
  for (int mk = 1; mk < 64; mk <<= 1) hing += __shfl_xor(hing, mk, 64);

  if (lane == 0)
    slossb[w] = (varp + hing * (1.0f / 15.0f) + 0.005f * regp) * (1.0f / 16.0f);
  __syncthreads();
  if (tid == 0) {
    float t = 0.f;
    #pragma unroll
    for (int i = 0; i < 8; ++i) t += slossb[i];
    out[0] = t * (1.0f / 9.0f);
  }
}

extern "C" void kernel_launch(void* const* d_in, const int* in_sizes, int n_in,
                              void* d_out, int out_size, void* d_ws, size_t ws_size,
                              hipStream_t stream)
{
  const float* feats = (const float*)d_in[0];
  const int*   labs  = (const int*)d_in[1];
  float* out = (float*)d_out;
  float* ws  = (float*)d_ws;

  (void)hipMemsetAsync(d_ws, 0, ZERO_BYTES, stream);
  hipLaunchKernelGGL(cl_accum,    dim3(512), dim3(512), 0, stream, feats, labs, ws);
  hipLaunchKernelGGL(cl_finalize, dim3(1),   dim3(512), 0, stream, ws, out);
}